// Round 2
// baseline (116.420 us; speedup 1.0000x reference)
//
#include <hip/hip_runtime.h>
#include <hip/hip_bf16.h>

// UncompressTransformLayer: scatter compressed strict-upper-triangular vector
// (row-major triu order, k=1) into a dense [n,n] fp32 matrix, zeros elsewhere.
// n = 8192, m = n*(n-1)/2 = 33,550,336.
//
// Memory-bound: 256 MiB write (all of out, every call) + 128 MiB read.
// Floor ~ 402 MB / 6.3 TB/s ~ 64 us. R1 was 100 us (4.0 TB/s).
// R2: nontemporal (nt) stores for the streaming output + 32B/thread/iter.

#define N_DIM 8192
#define UNITS_PER_ROW (N_DIM / 8)                       // 1024 units of 8 floats
#define TOTAL_UNITS (N_DIM * UNITS_PER_ROW)             // 8,388,608 (fits u32)

typedef float f32x4 __attribute__((ext_vector_type(4)));

__global__ void __launch_bounds__(256)
uncompress_kernel(const float* __restrict__ comp, float* __restrict__ out) {
    const unsigned stride = gridDim.x * blockDim.x;
    for (unsigned u = blockIdx.x * blockDim.x + threadIdx.x;
         u < (unsigned)TOTAL_UNITS; u += stride) {
        const unsigned i  = u >> 10;          // row  (u / 1024)
        const unsigned j0 = (u & 1023u) << 3; // starting column of this 8-unit

        f32x4 a, b;
        if (j0 + 7u <= i) {
            // entire unit at/below diagonal -> zeros
            a = (f32x4)0.f;
            b = (f32x4)0.f;
        } else {
            // compressed index for (i, j), j > i:
            //   idx = Offset(i) + (j - i - 1),  Offset(i) = i*(n-1) - i*(i-1)/2
            //   base = Offset(i) - i - 1  (idx = base + j; u32 wrap is benign)
            const unsigned off  = i * (N_DIM - 1) - ((i * (i - 1u)) >> 1);
            const unsigned base = off - i - 1u;
            if (j0 > i) {
                // fully above diagonal: 8 contiguous compressed reads
                const float* p = comp + (base + j0);
                a.x = p[0]; a.y = p[1]; a.z = p[2]; a.w = p[3];
                b.x = p[4]; b.y = p[5]; b.z = p[6]; b.w = p[7];
            } else {
                // straddles the diagonal: per-element predication
                a.x = (j0 + 0u > i) ? comp[base + j0 + 0u] : 0.f;
                a.y = (j0 + 1u > i) ? comp[base + j0 + 1u] : 0.f;
                a.z = (j0 + 2u > i) ? comp[base + j0 + 2u] : 0.f;
                a.w = (j0 + 3u > i) ? comp[base + j0 + 3u] : 0.f;
                b.x = (j0 + 4u > i) ? comp[base + j0 + 4u] : 0.f;
                b.y = (j0 + 5u > i) ? comp[base + j0 + 5u] : 0.f;
                b.z = (j0 + 6u > i) ? comp[base + j0 + 6u] : 0.f;
                b.w = (j0 + 7u > i) ? comp[base + j0 + 7u] : 0.f;
            }
        }
        // coalesced 2x16B nontemporal stores; out index = i*n + j0 (32B-aligned)
        f32x4* o = reinterpret_cast<f32x4*>(out + ((size_t)i << 13) + j0);
        __builtin_nontemporal_store(a, o);
        __builtin_nontemporal_store(b, o + 1);
    }
}

extern "C" void kernel_launch(void* const* d_in, const int* in_sizes, int n_in,
                              void* d_out, int out_size, void* d_ws, size_t ws_size,
                              hipStream_t stream) {
    const float* comp = (const float*)d_in[0];
    float* out = (float*)d_out;

    // 2048 blocks x 256 threads = 8 blocks/CU x 4 waves = 32 waves/CU (full);
    // each thread handles 16 units (grid-stride).
    const int block = 256;
    const int grid  = 2048;
    uncompress_kernel<<<grid, block, 0, stream>>>(comp, out);
}

// Round 3
// 93.168 us; speedup vs baseline: 1.2496x; 1.2496x over previous
//
#include <hip/hip_runtime.h>
#include <hip/hip_bf16.h>

// UncompressTransformLayer: scatter compressed strict-upper-triangular vector
// (row-major triu order, k=1) into a dense [n,n] fp32 matrix, zeros elsewhere.
// n = 8192, m = n*(n-1)/2 = 33,550,336.
//
// Memory-bound: 256 MiB write (all of out, every call) + 128 MiB read.
// Floor ~ 402 MB / 6.3 TB/s ~ 64 us.
// R1: scalar reads, plain stores           -> 100 us (4.0 TB/s)
// R2: nt stores + 8-wide units             -> 116 us (regressed; reverted)
// R3: aligned float4-pair reads + funnel select (reads now fully coalesced),
//     plain float4 stores, 4-wide units.

#define N_DIM 8192
#define M_TOTAL 33550336u                    // n*(n-1)/2
#define QUADS_PER_ROW (N_DIM / 4)            // 2048
#define TOTAL_QUADS (N_DIM * QUADS_PER_ROW)  // 16,777,216 (fits u32)

typedef float f32x4 __attribute__((ext_vector_type(4)));

__global__ void __launch_bounds__(256)
uncompress_kernel(const float* __restrict__ comp, float* __restrict__ out) {
    const unsigned stride = gridDim.x * blockDim.x;
    for (unsigned q = blockIdx.x * blockDim.x + threadIdx.x;
         q < (unsigned)TOTAL_QUADS; q += stride) {
        const unsigned i  = q >> 11;          // row  (q / 2048)
        const unsigned j0 = (q & 2047u) << 2; // starting column of this quad

        f32x4 v4;
        if (j0 + 3u <= i) {
            // entire quad at/below diagonal -> zeros
            v4 = (f32x4)0.f;
        } else {
            // compressed index for (i, j), j > i:
            //   idx = Offset(i) + (j - i - 1),  Offset(i) = i*(n-1) - i*(i-1)/2
            //   base = Offset(i) - i - 1  (idx = base + j)
            const unsigned off  = i * (N_DIM - 1) - ((i * (i - 1u)) >> 1);
            const unsigned base = off - i - 1u;   // u32 wrap only for i=0,
                                                  // never used with j<=i
            if (j0 > i) {
                // fully above diagonal: read the 16B-aligned quad pair that
                // covers comp[c0 .. c0+3], funnel-select by r = c0 & 3.
                // c0 >= Offset(i) >= 0, so no underflow here.
                const unsigned c0 = base + j0;
                const unsigned al = c0 & ~3u;
                const unsigned r  = __builtin_amdgcn_readfirstlane(c0 & 3u);
                const f32x4 v = *reinterpret_cast<const f32x4*>(comp + al);
                // clamp the +16B load; when the clamp engages (al+4 == m),
                // r is provably 0 and w is unused.
                const unsigned wi = (al + 4u <= M_TOTAL - 4u) ? (al + 4u)
                                                              : (M_TOTAL - 4u);
                const f32x4 w = *reinterpret_cast<const f32x4*>(comp + wi);
                switch (r) {
                    case 0: v4 = v; break;
                    case 1: v4 = (f32x4){v.y, v.z, v.w, w.x}; break;
                    case 2: v4 = (f32x4){v.z, v.w, w.x, w.y}; break;
                    default: v4 = (f32x4){v.w, w.x, w.y, w.z}; break;
                }
            } else {
                // straddles the diagonal (1 quad per row): scalar predicated
                v4.x = (j0 + 0u > i) ? comp[base + j0 + 0u] : 0.f;
                v4.y = (j0 + 1u > i) ? comp[base + j0 + 1u] : 0.f;
                v4.z = (j0 + 2u > i) ? comp[base + j0 + 2u] : 0.f;
                v4.w = (j0 + 3u > i) ? comp[base + j0 + 3u] : 0.f;
            }
        }
        // coalesced 16B store (normal, write-combines in L2)
        *reinterpret_cast<f32x4*>(out + ((size_t)i << 13) + j0) = v4;
    }
}

extern "C" void kernel_launch(void* const* d_in, const int* in_sizes, int n_in,
                              void* d_out, int out_size, void* d_ws, size_t ws_size,
                              hipStream_t stream) {
    const float* comp = (const float*)d_in[0];
    float* out = (float*)d_out;

    // 2048 blocks x 256 threads = 32 waves/CU (full); 32 quads per thread.
    const int block = 256;
    const int grid  = 2048;
    uncompress_kernel<<<grid, block, 0, stream>>>(comp, out);
}